// Round 2
// baseline (10288.495 us; speedup 1.0000x reference)
//
#include <hip/hip_runtime.h>
#include <hip/hip_bf16.h>
#include <cstdint>
#include <cstddef>

#define LOG2E 1.44269504088896340736f

using f32x4 = __attribute__((ext_vector_type(4))) float;
using s16x8 = __attribute__((ext_vector_type(8))) short;

static __device__ __forceinline__ float bf2f(unsigned short u) {
  union { unsigned int i; float f; } v; v.i = ((unsigned int)u) << 16; return v.f;
}
static __device__ __forceinline__ unsigned short f2bf(float f) {
  union { float f; unsigned int i; } v; v.f = f;
  unsigned int r = v.i + 0x7fffu + ((v.i >> 16) & 1u);
  return (unsigned short)(r >> 16);
}
static __device__ __forceinline__ float wredmax(float v) {
  #pragma unroll
  for (int m = 32; m > 0; m >>= 1) v = fmaxf(v, __shfl_xor(v, m, 64));
  return v;
}
static __device__ __forceinline__ float wredsum(float v) {
  #pragma unroll
  for (int m = 32; m > 0; m >>= 1) v += __shfl_xor(v, m, 64);
  return v;
}

// ---------------------------------------------------------------------------
// Transform kernel (unchanged from R1): pre-scale + re-tile weights.
// ---------------------------------------------------------------------------
__global__ void ktrans(const float* __restrict__ W1, const float* __restrict__ b1,
                       const float* __restrict__ Wih_in, const float* __restrict__ bih,
                       const float* __restrict__ Whh, const float* __restrict__ bhh,
                       const float* __restrict__ Wfc, const float* __restrict__ bfc,
                       const float* __restrict__ yhist,
                       unsigned short* __restrict__ WB1, unsigned short* __restrict__ WBhh,
                       float* __restrict__ W1eT, float* __restrict__ b1s,
                       float* __restrict__ Wihs, float* __restrict__ gbias,
                       float* __restrict__ yh2)
{
  int idx = blockIdx.x * 256 + threadIdx.x;
  const float TS = 2.f * LOG2E;
  if (idx < 131072) {                       // WB1: (k,e')
    int k = idx >> 8, e = idx & 255;
    WB1[((k >> 3) * 256 + e) * 8 + (k & 7)] = f2bf(TS * W1[e * 768 + k]);
    return;
  }
  idx -= 131072;
  if (idx < 262144) {                       // WBhh: (k,j)
    int k = idx >> 10, j = idx & 1023;
    float sc = ((j >> 8) == 2) ? TS : -LOG2E;
    WBhh[((k >> 3) * 1024 + j) * 8 + (k & 7)] = f2bf(sc * Whh[j * 256 + k]);
    return;
  }
  idx -= 262144;
  if (idx < 65536) {                        // W1eT: (e,e')
    int e = idx >> 8, ep = idx & 255;
    W1eT[idx] = TS * W1[ep * 768 + 512 + e];
    return;
  }
  idx -= 65536;
  if (idx < 256) { b1s[idx] = TS * b1[idx]; return; }
  idx -= 256;
  if (idx < 2048) {                         // Wihs (j,o)
    int j = idx >> 1;
    float sc = ((j >> 8) == 2) ? TS : -LOG2E;
    Wihs[idx] = sc * Wih_in[idx];
    return;
  }
  idx -= 2048;
  if (idx < 1024) {
    int j = idx;
    float sc = ((j >> 8) == 2) ? TS : -LOG2E;
    gbias[j] = sc * (bih[j] + bhh[j]);
    return;
  }
  idx -= 1024;
  if (idx < 4096) {                         // yh2 (b,o)
    int bq = idx >> 1, o = idx & 1;
    float a = bfc[o];
    for (int t = 0; t < 64; ++t) a = fmaf(yhist[bq * 64 + t], Wfc[o * 320 + 256 + t], a);
    yh2[idx] = a;
    return;
  }
}

// ---------------------------------------------------------------------------
// Precompute kernel (unchanged from R1): P[b][ec][t][8] bf16, ey[b][t][0:2].
// ---------------------------------------------------------------------------
__global__ __launch_bounds__(256, 4) void kpre(
    const float* __restrict__ x, const float* __restrict__ W1eT,
    const float* __restrict__ b1s, const float* __restrict__ Wfc,
    unsigned short* __restrict__ P, float* __restrict__ ey)
{
  __shared__ __align__(16) unsigned short st[64 * 264];
  const int bq = blockIdx.x;
  const int tid = threadIdx.x;              // e' = tid
  float acc[64];
  const float bb1 = b1s[tid];
  #pragma unroll
  for (int r = 0; r < 64; ++r) acc[r] = bb1;
  const float* __restrict__ xb = x + (size_t)bq * 64 * 256;
  for (int e4 = 0; e4 < 64; ++e4) {
    float wv[4];
    #pragma unroll
    for (int j2 = 0; j2 < 4; ++j2) wv[j2] = W1eT[(e4 * 4 + j2) * 256 + tid];
    #pragma unroll
    for (int r = 0; r < 64; ++r) {
      #pragma unroll
      for (int j2 = 0; j2 < 4; ++j2)
        acc[r] = fmaf(wv[j2], xb[r * 256 + e4 * 4 + j2], acc[r]);
    }
  }
  #pragma unroll
  for (int r = 0; r < 64; ++r) st[r * 264 + tid] = f2bf(acc[r]);
  __syncthreads();
  unsigned int* __restrict__ Pd = (unsigned int*)P;
  for (int d = tid; d < 8192; d += 256) {
    int f = d * 2;
    int ec = f >> 9, t = (f >> 3) & 63, i0 = f & 7;
    unsigned int lo = st[t * 264 + ec * 8 + i0];
    unsigned int hi = st[t * 264 + ec * 8 + i0 + 1];
    Pd[(size_t)bq * 8192 + d] = lo | (hi << 16);
  }
  if (tid < 128) {
    int t = tid >> 1, o = tid & 1;
    float a = 0.f;
    const float* __restrict__ xr = xb + t * 256;
    const float* __restrict__ wr = Wfc + o * 320;
    #pragma unroll 4
    for (int e = 0; e < 256; ++e) a = fmaf(xr[e], wr[e], a);
    ey[((size_t)bq * 64 + t) * 2 + o] = a;
  }
}

// ---------------------------------------------------------------------------
// Recurrence v2: P register-resident (128 VGPR/lane), pointwise in-register,
// c-state in f32 regs, 3 barriers/step, zero per-step HBM traffic.
// 256 blocks x 8 rows, 8 waves (wave = batch row).
// ---------------------------------------------------------------------------
__global__ __launch_bounds__(512, 2) void krecur(
    const float* __restrict__ x, const float* __restrict__ w2g,
    const unsigned short* __restrict__ WB1, const unsigned short* __restrict__ WBhh,
    const float* __restrict__ Wih, const float* __restrict__ gbias,
    const float* __restrict__ yh2, const float* __restrict__ ey,
    const unsigned short* __restrict__ P,
    const float* __restrict__ Wfin, const float* __restrict__ bfin,
    float* __restrict__ out)
{
  // hcA: bf16 state in MFMA-A-fragment order: [k>>3][row][k&7], k<512 ([h|c])
  __shared__ __align__(16) unsigned short hcA[4096];   // 8 KB
  __shared__ __align__(16) float qf[8][256];           // 8 KB
  __shared__ __align__(16) float w2f[256];             // 1 KB
  __shared__ __align__(16) float wi0S[1024];           // 4 KB
  __shared__ __align__(16) float wi1S[1024];           // 4 KB
  __shared__ __align__(16) float gbS[1024];            // 4 KB
  __shared__ __align__(16) float scA[8][64];           // 2 KB
  __shared__ float yt[8][2];
  __shared__ __align__(16) float hF[8][256];           // 8 KB
  __shared__ __align__(16) float ctxS[8][256];         // 8 KB

  const int tid = threadIdx.x;
  const int w = tid >> 6, lane = tid & 63;
  const int b = w;                           // wave-per-row mapping
  const int gb = blockIdx.x * 8 + b;

  for (int i = tid; i < 4096; i += 512) hcA[i] = 0;
  if (tid < 256) w2f[tid] = w2g[tid];
  for (int j = tid; j < 1024; j += 512) {
    wi0S[j] = Wih[2 * j];
    wi1S[j] = Wih[2 * j + 1];
    gbS[j]  = gbias[j];
  }

  // ---- preload this wave's P row into 128 VGPRs (one-time HBM read) ----
  s16x8 Preg[32];
  const unsigned short* __restrict__ Pb = P + (size_t)gb * 16384;
  #pragma unroll
  for (int ec = 0; ec < 32; ++ec)
    Preg[ec] = *(const s16x8*)(Pb + (size_t)(ec * 64 + lane) * 8);
  const float2 eyv = *(const float2*)(ey + ((size_t)gb * 64 + lane) * 2);
  const float yh0 = yh2[gb * 2], yh1 = yh2[gb * 2 + 1];

  __syncthreads();

  const int frow = lane & 7;    // A-frag row (rows 8..15 duplicate 0..7)
  const int fgrp = lane >> 4;   // k-group
  const int fcol = lane & 15;   // B/D col
  const int drow0 = fgrp * 4;   // D row base

  float creg[8];                // c state: [cg*4+r], f32
  #pragma unroll
  for (int i = 0; i < 8; ++i) creg[i] = 0.f;

  for (int s = 0; s < 64; ++s) {
    // ---- h-part A fragments (kept live through gates) ----
    s16x8 afh[8];
    #pragma unroll
    for (int kb = 0; kb < 8; ++kb)
      afh[kb] = *(const s16x8*)&hcA[((kb * 4 + fgrp) * 8 + frow) * 8];

    // ---- Q phase: q = hc @ W1hc_s^T  (2 N-tiles per wave) ----
    #pragma unroll
    for (int et2 = 0; et2 < 2; ++et2) {
      const int eb = (w * 2 + et2) * 16;
      f32x4 acc = {0.f, 0.f, 0.f, 0.f};
      #pragma unroll
      for (int kb = 0; kb < 8; ++kb) {
        s16x8 bfr = *(const s16x8*)&WB1[(size_t)((kb * 4 + fgrp) * 256 + eb + fcol) * 8];
        acc = __builtin_amdgcn_mfma_f32_16x16x32_bf16(afh[kb], bfr, acc, 0, 0, 0);
      }
      #pragma unroll
      for (int kb = 8; kb < 16; ++kb) {      // c-part A frags: transient reads
        s16x8 ac = *(const s16x8*)&hcA[((kb * 4 + fgrp) * 8 + frow) * 8];
        s16x8 bfr = *(const s16x8*)&WB1[(size_t)((kb * 4 + fgrp) * 256 + eb + fcol) * 8];
        acc = __builtin_amdgcn_mfma_f32_16x16x32_bf16(ac, bfr, acc, 0, 0, 0);
      }
      if (lane < 32) {
        #pragma unroll
        for (int r = 0; r < 4; ++r) qf[drow0 + r][eb + fcol] = acc[r];
      }
    }
    __syncthreads();

    // ---- scores + softmax + ytilde (lane = t, P in regs, q/w2 via LDS bcast) ----
    {
      float a0 = 0.f, a1 = 0.f, a2 = 0.f, a3 = 0.f;
      const float* __restrict__ qrow = &qf[b][0];
      #pragma unroll
      for (int ec = 0; ec < 32; ++ec) {
        s16x8 pv = Preg[ec];
        float4 qa = *(const float4*)(qrow + ec * 8);
        float4 qb4 = *(const float4*)(qrow + ec * 8 + 4);
        float4 wa = *(const float4*)(w2f + ec * 8);
        float4 wb4 = *(const float4*)(w2f + ec * 8 + 4);
        a0 = fmaf(wa.x, __builtin_amdgcn_rcpf(1.f + __builtin_amdgcn_exp2f(bf2f((unsigned short)pv[0]) + qa.x)), a0);
        a1 = fmaf(wa.y, __builtin_amdgcn_rcpf(1.f + __builtin_amdgcn_exp2f(bf2f((unsigned short)pv[1]) + qa.y)), a1);
        a2 = fmaf(wa.z, __builtin_amdgcn_rcpf(1.f + __builtin_amdgcn_exp2f(bf2f((unsigned short)pv[2]) + qa.z)), a2);
        a3 = fmaf(wa.w, __builtin_amdgcn_rcpf(1.f + __builtin_amdgcn_exp2f(bf2f((unsigned short)pv[3]) + qa.w)), a3);
        a0 = fmaf(wb4.x, __builtin_amdgcn_rcpf(1.f + __builtin_amdgcn_exp2f(bf2f((unsigned short)pv[4]) + qb4.x)), a0);
        a1 = fmaf(wb4.y, __builtin_amdgcn_rcpf(1.f + __builtin_amdgcn_exp2f(bf2f((unsigned short)pv[5]) + qb4.y)), a1);
        a2 = fmaf(wb4.z, __builtin_amdgcn_rcpf(1.f + __builtin_amdgcn_exp2f(bf2f((unsigned short)pv[6]) + qb4.z)), a2);
        a3 = fmaf(wb4.w, __builtin_amdgcn_rcpf(1.f + __builtin_amdgcn_exp2f(bf2f((unsigned short)pv[7]) + qb4.w)), a3);
      }
      float sc = -2.f * ((a0 + a1) + (a2 + a3));
      float mx = wredmax(sc);
      float e_t = __builtin_amdgcn_exp2f((sc - mx) * LOG2E);
      float sm = wredsum(e_t);
      float alpha = e_t * __builtin_amdgcn_rcpf(sm);
      if (s == 63) scA[b][lane] = alpha;
      float y0 = wredsum(alpha * eyv.x);
      float y1 = wredsum(alpha * eyv.y);
      if (lane == 0) {
        yt[b][0] = y0 + yh0;
        yt[b][1] = y1 + yh1;
      }
    }
    __syncthreads();

    // ---- gates: wave w owns j-cols {w*16..+15} x {cg=0,1}*128 x 4 gates ----
    f32x4 gacc[2][4];
    #pragma unroll
    for (int cg = 0; cg < 2; ++cg) {
      #pragma unroll
      for (int g = 0; g < 4; ++g) {
        const int j = g * 256 + cg * 128 + w * 16 + fcol;
        const float wi0 = wi0S[j], wi1 = wi1S[j], gbj = gbS[j];
        f32x4 a;
        #pragma unroll
        for (int r = 0; r < 4; ++r) {
          const int br = (drow0 + r) & 7;
          a[r] = fmaf(wi0, yt[br][0], fmaf(wi1, yt[br][1], gbj));
        }
        #pragma unroll
        for (int kb = 0; kb < 8; ++kb) {
          s16x8 bfr = *(const s16x8*)&WBhh[(size_t)((kb * 4 + fgrp) * 1024 + j) * 8];
          a = __builtin_amdgcn_mfma_f32_16x16x32_bf16(afh[kb], bfr, a, 0, 0, 0);
        }
        gacc[cg][g] = a;
      }
    }

    // ---- pointwise entirely in registers ----
    #pragma unroll
    for (int cg = 0; cg < 2; ++cg) {
      #pragma unroll
      for (int r = 0; r < 4; ++r) {
        const int row = (drow0 + r) & 7;
        const int jj = cg * 128 + w * 16 + fcol;
        const float gi = gacc[cg][0][r];
        const float gf = gacc[cg][1][r];
        const float gg = gacc[cg][2][r];
        const float go = gacc[cg][3][r];
        const float si = __builtin_amdgcn_rcpf(1.f + __builtin_amdgcn_exp2f(gi));
        const float sf = __builtin_amdgcn_rcpf(1.f + __builtin_amdgcn_exp2f(gf));
        const float tg = 1.f - 2.f * __builtin_amdgcn_rcpf(1.f + __builtin_amdgcn_exp2f(gg));
        const float so = __builtin_amdgcn_rcpf(1.f + __builtin_amdgcn_exp2f(go));
        const float cn = sf * creg[cg * 4 + r] + si * tg;
        creg[cg * 4 + r] = cn;
        const float th = 1.f - 2.f * __builtin_amdgcn_rcpf(1.f + __builtin_amdgcn_exp2f(2.f * LOG2E * cn));
        const float hn = so * th;
        if (lane < 32) {
          hcA[((jj >> 3) * 8 + row) * 8 + (jj & 7)] = f2bf(hn);
          hcA[((32 + (jj >> 3)) * 8 + row) * 8 + (jj & 7)] = f2bf(cn);
          if (s == 63) hF[row][jj] = hn;
        }
      }
    }
    __syncthreads();

    if (s == 63) {   // ctx[b][e] = sum_t alpha_t * x[b,t,e]
      #pragma unroll
      for (int p = 0; p < 4; ++p) {
        const int e = p * 64 + lane;
        float a = 0.f;
        const float* __restrict__ xr = x + (size_t)gb * 64 * 256 + e;
        #pragma unroll 8
        for (int t = 0; t < 64; ++t) a = fmaf(scA[b][t], xr[t * 256], a);
        ctxS[b][e] = a;
      }
      __syncthreads();
    }
  }

  // ---- final: out = [h, ctx] @ W_final.T + b_final ----
  {
    float o0 = 0.f, o1 = 0.f;
    #pragma unroll
    for (int kk = 0; kk < 8; ++kk) {
      const int k = kk * 64 + lane;
      const float v = (k < 256) ? hF[b][k] : ctxS[b][k - 256];
      o0 = fmaf(v, Wfin[k], o0);
      o1 = fmaf(v, Wfin[512 + k], o1);
    }
    o0 = wredsum(o0);
    o1 = wredsum(o1);
    if (lane == 0) {
      out[gb * 2 + 0] = o0 + bfin[0];
      out[gb * 2 + 1] = o1 + bfin[1];
    }
  }
}

// ---------------------------------------------------------------------------
extern "C" void kernel_launch(void* const* d_in, const int* in_sizes, int n_in,
                              void* d_out, int out_size, void* d_ws, size_t ws_size,
                              hipStream_t stream) {
  const float* x    = (const float*)d_in[0];
  const float* yh   = (const float*)d_in[1];
  const float* W1   = (const float*)d_in[2];
  const float* b1   = (const float*)d_in[3];
  const float* w2   = (const float*)d_in[4];
  // d_in[5] = b2: additive constant on scores, softmax-invariant -> unused
  const float* Wih  = (const float*)d_in[6];
  const float* bih  = (const float*)d_in[7];
  const float* Whh  = (const float*)d_in[8];
  const float* bhh  = (const float*)d_in[9];
  const float* Wfc  = (const float*)d_in[10];
  const float* bfc  = (const float*)d_in[11];
  const float* Wfin = (const float*)d_in[12];
  const float* bfin = (const float*)d_in[13];

  char* ws = (char*)d_ws;
  unsigned short* P    = (unsigned short*)(ws + 0);          // 67,108,864 B
  unsigned short* WB1  = (unsigned short*)(ws + 67108864);   //    262,144 B
  unsigned short* WBhh = (unsigned short*)(ws + 67371008);   //    524,288 B
  float* W1eT  = (float*)(ws + 67895296);                    //    262,144 B
  float* b1s   = (float*)(ws + 68157440);                    //      1,024 B
  float* Wihs  = (float*)(ws + 68158464);                    //      8,192 B
  float* gbias = (float*)(ws + 68166656);                    //      4,096 B
  float* yh2   = (float*)(ws + 68170752);                    //     16,384 B
  float* ey    = (float*)(ws + 68187136);                    //  1,048,576 B -> 69,235,712 total

  ktrans<<<1821, 256, 0, stream>>>(W1, b1, Wih, bih, Whh, bhh, Wfc, bfc, yh,
                                   WB1, WBhh, W1eT, b1s, Wihs, gbias, yh2);
  kpre<<<2048, 256, 0, stream>>>(x, W1eT, b1s, Wfc, P, ey);
  krecur<<<256, 512, 0, stream>>>(x, w2, WB1, WBhh, Wihs, gbias, yh2, ey, P,
                                  Wfin, bfin, (float*)d_out);
}

// Round 3
// 7068.375 us; speedup vs baseline: 1.4556x; 1.4556x over previous
//
#include <hip/hip_runtime.h>
#include <hip/hip_bf16.h>
#include <cstdint>
#include <cstddef>

#define LOG2E 1.44269504088896340736f

using f32x4 = __attribute__((ext_vector_type(4))) float;
using s16x8 = __attribute__((ext_vector_type(8))) short;

static __device__ __forceinline__ float bf2f(unsigned short u) {
  union { unsigned int i; float f; } v; v.i = ((unsigned int)u) << 16; return v.f;
}
static __device__ __forceinline__ unsigned short f2bf(float f) {
  union { float f; unsigned int i; } v; v.f = f;
  unsigned int r = v.i + 0x7fffu + ((v.i >> 16) & 1u);
  return (unsigned short)(r >> 16);
}
static __device__ __forceinline__ float wredmax(float v) {
  #pragma unroll
  for (int m = 32; m > 0; m >>= 1) v = fmaxf(v, __shfl_xor(v, m, 64));
  return v;
}
static __device__ __forceinline__ float wredsum(float v) {
  #pragma unroll
  for (int m = 32; m > 0; m >>= 1) v += __shfl_xor(v, m, 64);
  return v;
}

// ---------------------------------------------------------------------------
// Transform kernel: pre-scale + re-tile weights, fold constants.
//  WB1  [k>>3][e'][k&7] bf16 = 2log2e * W1[e'][k]        (k<512, hc part)
//  WBhh [k>>3][j ][k&7] bf16 = scale(j) * W_hh[j][k]
//  WB1e [k>>3][e'][k&7] bf16 = 2log2e * W1[e'][512+k]    (k<256, x part)
//  b1s, Wihs, gbias, yh2 as before.
// ---------------------------------------------------------------------------
__global__ void ktrans(const float* __restrict__ W1, const float* __restrict__ b1,
                       const float* __restrict__ Wih_in, const float* __restrict__ bih,
                       const float* __restrict__ Whh, const float* __restrict__ bhh,
                       const float* __restrict__ Wfc, const float* __restrict__ bfc,
                       const float* __restrict__ yhist,
                       unsigned short* __restrict__ WB1, unsigned short* __restrict__ WBhh,
                       unsigned short* __restrict__ WB1e, float* __restrict__ b1s,
                       float* __restrict__ Wihs, float* __restrict__ gbias,
                       float* __restrict__ yh2)
{
  int idx = blockIdx.x * 256 + threadIdx.x;
  const float TS = 2.f * LOG2E;
  if (idx < 131072) {                       // WB1: (k,e')
    int k = idx >> 8, e = idx & 255;
    WB1[((k >> 3) * 256 + e) * 8 + (k & 7)] = f2bf(TS * W1[e * 768 + k]);
    return;
  }
  idx -= 131072;
  if (idx < 262144) {                       // WBhh: (k,j)
    int k = idx >> 10, j = idx & 1023;
    float sc = ((j >> 8) == 2) ? TS : -LOG2E;
    WBhh[((k >> 3) * 1024 + j) * 8 + (k & 7)] = f2bf(sc * Whh[j * 256 + k]);
    return;
  }
  idx -= 262144;
  if (idx < 65536) {                        // WB1e: (k,e'), x part
    int k = idx >> 8, e = idx & 255;
    WB1e[((k >> 3) * 256 + e) * 8 + (k & 7)] = f2bf(TS * W1[e * 768 + 512 + k]);
    return;
  }
  idx -= 65536;
  if (idx < 256) { b1s[idx] = TS * b1[idx]; return; }
  idx -= 256;
  if (idx < 2048) {                         // Wihs (j,o)
    int j = idx >> 1;
    float sc = ((j >> 8) == 2) ? TS : -LOG2E;
    Wihs[idx] = sc * Wih_in[idx];
    return;
  }
  idx -= 2048;
  if (idx < 1024) {
    int j = idx;
    float sc = ((j >> 8) == 2) ? TS : -LOG2E;
    gbias[j] = sc * (bih[j] + bhh[j]);
    return;
  }
  idx -= 1024;
  if (idx < 4096) {                         // yh2 (b,o)
    int bq = idx >> 1, o = idx & 1;
    float a = bfc[o];
    for (int t = 0; t < 64; ++t) a = fmaf(yhist[bq * 64 + t], Wfc[o * 320 + 256 + t], a);
    yh2[idx] = a;
    return;
  }
}

// ---------------------------------------------------------------------------
// Precompute kernel v2 (MFMA): P[b][ec][t][8] bf16 = 2log2e*(x[b,t,:]@W1e.T)
// (b1 NOT included; added in krecur). Plus ey[b][t][0:2].
// One block per batch row; 4 waves, wave w = M-tile mt.
// ---------------------------------------------------------------------------
__global__ __launch_bounds__(256, 4) void kpre(
    const float* __restrict__ x, const unsigned short* __restrict__ WB1e,
    const float* __restrict__ Wfc,
    unsigned short* __restrict__ P, float* __restrict__ ey)
{
  __shared__ __align__(16) unsigned short xs[16384];   // 32 KB: x bf16 / P staging
  const int bq = blockIdx.x;
  const int tid = threadIdx.x;
  const int w = tid >> 6, lane = tid & 63;
  const float* __restrict__ xb = x + (size_t)bq * 16384;

  // 1. load x (f32), convert bf16, swizzled LDS store
  #pragma unroll 4
  for (int it = 0; it < 16; ++it) {
    int idx = it * 256 + tid;                 // float4 index
    float4 v = *(const float4*)(xb + (size_t)idx * 4);
    int t = idx >> 6, e0 = (idx & 63) * 4;
    unsigned long long pk = (unsigned long long)f2bf(v.x)
        | ((unsigned long long)f2bf(v.y) << 16)
        | ((unsigned long long)f2bf(v.z) << 32)
        | ((unsigned long long)f2bf(v.w) << 48);
    int ba = (t * 512 + e0 * 2) ^ ((t & 7) << 4);
    *(unsigned long long*)((char*)xs + ba) = pk;
  }
  __syncthreads();

  // 2. A-frags for this wave's mt = w
  const int mt = w;
  const int fgrp = lane >> 4, fcol = lane & 15;
  const int trow = mt * 16 + fcol;            // A row = lane&15
  s16x8 af[8];
  #pragma unroll
  for (int kb = 0; kb < 8; ++kb) {
    int e = kb * 32 + fgrp * 8;
    int ba = (trow * 512 + e * 2) ^ ((trow & 7) << 4);
    af[kb] = *(const s16x8*)((char*)xs + ba);
  }
  __syncthreads();                            // xs now reusable as Pst [t][e']

  unsigned short* __restrict__ Pst = xs;
  #pragma unroll
  for (int nt = 0; nt < 16; ++nt) {
    s16x8 bfr[8];
    #pragma unroll
    for (int kb = 0; kb < 8; ++kb)
      bfr[kb] = *(const s16x8*)&WB1e[(size_t)((kb * 4 + fgrp) * 256 + nt * 16 + fcol) * 8];
    f32x4 acc = {0.f, 0.f, 0.f, 0.f};
    #pragma unroll
    for (int kb = 0; kb < 8; ++kb)
      acc = __builtin_amdgcn_mfma_f32_16x16x32_bf16(af[kb], bfr[kb], acc, 0, 0, 0);
    const int ep = nt * 16 + fcol;            // D: col=lane&15, row=fgrp*4+r
    #pragma unroll
    for (int r = 0; r < 4; ++r)
      Pst[(mt * 16 + fgrp * 4 + r) * 256 + ep] = f2bf(acc[r]);
  }
  __syncthreads();

  // 3. coalesced global write: P[bq][ec][t][8]
  unsigned int* __restrict__ Pd = (unsigned int*)(P + (size_t)bq * 16384);
  #pragma unroll 4
  for (int d = tid; d < 8192; d += 256) {
    int f = d * 2;                            // u16 idx: ec*512 + t*8 + i0
    int ec = f >> 9, t = (f >> 3) & 63, i0 = f & 7;
    unsigned int lo = Pst[t * 256 + ec * 8 + i0];
    unsigned int hi = Pst[t * 256 + ec * 8 + i0 + 1];
    Pd[d] = lo | (hi << 16);
  }

  // 4. ey[bq][t][o] = x[bq,t,:] . Wfc[o][0:256]
  if (tid < 128) {
    int t = tid >> 1, o = tid & 1;
    float a = 0.f;
    const float* __restrict__ xr = xb + t * 256;
    const float* __restrict__ wr = Wfc + o * 320;
    #pragma unroll 4
    for (int e = 0; e < 256; ++e) a = fmaf(xr[e], wr[e], a);
    ey[((size_t)bq * 64 + t) * 2 + o] = a;
  }
}

// ---------------------------------------------------------------------------
// Recurrence v3: P split 24 reg-chunks (96 VGPR) + 8 LDS chunks (64 KB).
// Gates-MFMA made yt-independent (yt added post-MFMA) so the WBhh L2 stream
// interleaves with scores VALU. 3 barriers/step. 256 blocks x 512 thr.
// ---------------------------------------------------------------------------
__global__ __launch_bounds__(512, 2) void krecur(
    const float* __restrict__ x, const float* __restrict__ w2g,
    const unsigned short* __restrict__ WB1, const unsigned short* __restrict__ WBhh,
    const float* __restrict__ Wihs, const float* __restrict__ gbias,
    const float* __restrict__ b1s, const float* __restrict__ yh2,
    const float* __restrict__ ey, const unsigned short* __restrict__ P,
    const float* __restrict__ Wfin, const float* __restrict__ bfin,
    float* __restrict__ out)
{
  __shared__ __align__(16) unsigned short hcA[4096];      // 8 KB  [k>>3][row][k&7]
  __shared__ __align__(16) unsigned short P8[8][8][64][8];// 64 KB  ec 24..31; ctx alias
  __shared__ __align__(16) float qf[8][256];              // 8 KB; h(f32) alias at s=63
  __shared__ __align__(16) float w2f[256];                // 1 KB
  __shared__ __align__(16) float b1f[256];                // 1 KB
  __shared__ __align__(16) float wi0S[1024];              // 4 KB
  __shared__ __align__(16) float wi1S[1024];              // 4 KB
  __shared__ __align__(16) float gbS[1024];               // 4 KB
  __shared__ __align__(16) float scAl[8][64];             // 2 KB
  __shared__ float yt[8][2];

  const int tid = threadIdx.x;
  const int w = tid >> 6, lane = tid & 63;
  const int b = w;                            // wave = batch row
  const int gbase = blockIdx.x * 8;
  const int gb = gbase + b;

  for (int i = tid; i < 4096; i += 512) hcA[i] = 0;
  if (tid < 256) { w2f[tid] = w2g[tid]; b1f[tid] = b1s[tid]; }
  for (int j = tid; j < 1024; j += 512) {
    wi0S[j] = Wihs[2 * j]; wi1S[j] = Wihs[2 * j + 1]; gbS[j] = gbias[j];
  }
  // P LDS chunks (ec 24..31) for all 8 rows
  for (int i = tid; i < 4096; i += 512) {
    int row = i >> 9, jj = i & 511;
    int ecp = jj >> 6, t = jj & 63;
    *(s16x8*)&P8[row][ecp][t][0] =
        *(const s16x8*)(P + (size_t)(gbase + row) * 16384 + (size_t)((24 + ecp) * 64 + t) * 8);
  }
  // P reg chunks (ec 0..23): 96 VGPR
  s16x8 Preg[24];
  const unsigned short* __restrict__ Pb = P + (size_t)gb * 16384;
  #pragma unroll
  for (int ec = 0; ec < 24; ++ec)
    Preg[ec] = *(const s16x8*)(Pb + (size_t)(ec * 64 + lane) * 8);
  const float2 eyv = *(const float2*)(ey + ((size_t)gb * 64 + lane) * 2);
  const float yh0 = yh2[gb * 2], yh1 = yh2[gb * 2 + 1];
  __syncthreads();

  const int frow = lane & 7;
  const int fgrp = lane >> 4;
  const int fcol = lane & 15;
  const int drow0 = fgrp * 4;
  const float b1r0 = b1f[(w * 2 + 0) * 16 + fcol];
  const float b1r1 = b1f[(w * 2 + 1) * 16 + fcol];

  float creg[8];
  #pragma unroll
  for (int i = 0; i < 8; ++i) creg[i] = 0.f;

  for (int s = 0; s < 64; ++s) {
    // ---- h-part A fragments ----
    s16x8 afh[8];
    #pragma unroll
    for (int kb = 0; kb < 8; ++kb)
      afh[kb] = *(const s16x8*)&hcA[((kb * 4 + fgrp) * 8 + frow) * 8];

    // ---- Q: q = hc @ WB1^T + b1  (2 N-tiles/wave) ----
    #pragma unroll
    for (int et2 = 0; et2 < 2; ++et2) {
      const int eb = (w * 2 + et2) * 16;
      s16x8 bfr[8];
      #pragma unroll
      for (int kb = 0; kb < 8; ++kb)
        bfr[kb] = *(const s16x8*)&WB1[(size_t)((kb * 4 + fgrp) * 256 + eb + fcol) * 8];
      f32x4 acc = {0.f, 0.f, 0.f, 0.f};
      #pragma unroll
      for (int kb = 0; kb < 8; ++kb)
        acc = __builtin_amdgcn_mfma_f32_16x16x32_bf16(afh[kb], bfr[kb], acc, 0, 0, 0);
      #pragma unroll
      for (int kb = 8; kb < 16; ++kb) {       // c-part: transient A reads
        s16x8 ac = *(const s16x8*)&hcA[((kb * 4 + fgrp) * 8 + frow) * 8];
        s16x8 bc = *(const s16x8*)&WB1[(size_t)((kb * 4 + fgrp) * 256 + eb + fcol) * 8];
        acc = __builtin_amdgcn_mfma_f32_16x16x32_bf16(ac, bc, acc, 0, 0, 0);
      }
      if (lane < 32) {
        const float bb = et2 ? b1r1 : b1r0;
        #pragma unroll
        for (int r = 0; r < 4; ++r) qf[drow0 + r][eb + fcol] = acc[r] + bb;
      }
    }
    __syncthreads();

    // ---- phase2: gates-MFMA (WBhh L2 stream) interleaved with scores VALU ----
    float a0 = 0.f, a1 = 0.f, a2 = 0.f, a3 = 0.f;
    f32x4 gacc[2][4];
    const float* __restrict__ qrow = &qf[b][0];
    #pragma unroll
    for (int u = 0; u < 8; ++u) {
      const int cg = u >> 2, g = u & 3;
      const int j = g * 256 + cg * 128 + w * 16 + fcol;
      s16x8 bfr[8];
      #pragma unroll
      for (int kb = 0; kb < 8; ++kb)
        bfr[kb] = *(const s16x8*)&WBhh[(size_t)((kb * 4 + fgrp) * 1024 + j) * 8];
      // scores chunk: ec = u*4 .. u*4+3 (VALU fills load latency)
      #pragma unroll
      for (int q4 = 0; q4 < 4; ++q4) {
        const int ec = u * 4 + q4;
        s16x8 pv;
        if (ec < 24) pv = Preg[ec];
        else         pv = *(const s16x8*)&P8[b][ec - 24][lane][0];
        float4 qa  = *(const float4*)(qrow + ec * 8);
        float4 qb4 = *(const float4*)(qrow + ec * 8 + 4);
        float4 wa  = *(const float4*)(w2f + ec * 8);
        float4 wb4 = *(const float4*)(w2f + ec * 8 + 4);
        a0 = fmaf(wa.x, __builtin_amdgcn_rcpf(1.f + __builtin_amdgcn_exp2f(bf2f((unsigned short)pv[0]) + qa.x)), a0);
        a1 = fmaf(wa.y, __builtin_amdgcn_rcpf(1.f + __builtin_amdgcn_exp2f(bf2f((unsigned short)pv[1]) + qa.y)), a1);
        a2 = fmaf(wa.z, __builtin_amdgcn_rcpf(1.f + __builtin_amdgcn_exp2f(bf2f((unsigned short)pv[2]) + qa.z)), a2);
        a3 = fmaf(wa.w, __builtin_amdgcn_rcpf(1.f + __builtin_amdgcn_exp2f(bf2f((unsigned short)pv[3]) + qa.w)), a3);
        a0 = fmaf(wb4.x, __builtin_amdgcn_rcpf(1.f + __builtin_amdgcn_exp2f(bf2f((unsigned short)pv[4]) + qb4.x)), a0);
        a1 = fmaf(wb4.y, __builtin_amdgcn_rcpf(1.f + __builtin_amdgcn_exp2f(bf2f((unsigned short)pv[5]) + qb4.y)), a1);
        a2 = fmaf(wb4.z, __builtin_amdgcn_rcpf(1.f + __builtin_amdgcn_exp2f(bf2f((unsigned short)pv[6]) + qb4.z)), a2);
        a3 = fmaf(wb4.w, __builtin_amdgcn_rcpf(1.f + __builtin_amdgcn_exp2f(bf2f((unsigned short)pv[7]) + qb4.w)), a3);
      }
      const float gbj = gbS[j];
      f32x4 a = {gbj, gbj, gbj, gbj};
      #pragma unroll
      for (int kb = 0; kb < 8; ++kb)
        a = __builtin_amdgcn_mfma_f32_16x16x32_bf16(afh[kb], bfr[kb], a, 0, 0, 0);
      gacc[cg][g] = a;
    }
    // softmax + ytilde
    {
      float sc = -2.f * ((a0 + a1) + (a2 + a3));
      float mx = wredmax(sc);
      float e_t = __builtin_amdgcn_exp2f((sc - mx) * LOG2E);
      float sm = wredsum(e_t);
      float alpha = e_t * __builtin_amdgcn_rcpf(sm);
      if (s == 63) scAl[b][lane] = alpha;
      float y0 = wredsum(alpha * eyv.x);
      float y1 = wredsum(alpha * eyv.y);
      if (lane == 0) { yt[b][0] = y0 + yh0; yt[b][1] = y1 + yh1; }
    }
    __syncthreads();

    // ---- phase3: + wi*yt, pointwise, state update ----
    #pragma unroll
    for (int cg = 0; cg < 2; ++cg) {
      const int jj = cg * 128 + w * 16 + fcol;
      float wi0g[4], wi1g[4];
      #pragma unroll
      for (int g = 0; g < 4; ++g) { wi0g[g] = wi0S[g * 256 + jj]; wi1g[g] = wi1S[g * 256 + jj]; }
      #pragma unroll
      for (int r = 0; r < 4; ++r) {
        const int row = (drow0 + r) & 7;
        const float y0v = yt[row][0], y1v = yt[row][1];
        const float gi = gacc[cg][0][r] + fmaf(wi0g[0], y0v, wi1g[0] * y1v);
        const float gf = gacc[cg][1][r] + fmaf(wi0g[1], y0v, wi1g[1] * y1v);
        const float gg = gacc[cg][2][r] + fmaf(wi0g[2], y0v, wi1g[2] * y1v);
        const float go = gacc[cg][3][r] + fmaf(wi0g[3], y0v, wi1g[3] * y1v);
        const float si = __builtin_amdgcn_rcpf(1.f + __builtin_amdgcn_exp2f(gi));
        const float sf = __builtin_amdgcn_rcpf(1.f + __builtin_amdgcn_exp2f(gf));
        const float tg = 1.f - 2.f * __builtin_amdgcn_rcpf(1.f + __builtin_amdgcn_exp2f(gg));
        const float so = __builtin_amdgcn_rcpf(1.f + __builtin_amdgcn_exp2f(go));
        const float cn = sf * creg[cg * 4 + r] + si * tg;
        creg[cg * 4 + r] = cn;
        const float th = 1.f - 2.f * __builtin_amdgcn_rcpf(1.f + __builtin_amdgcn_exp2f(2.f * LOG2E * cn));
        const float hn = so * th;
        if (lane < 32) {
          hcA[((jj >> 3) * 8 + row) * 8 + (jj & 7)] = f2bf(hn);
          hcA[((32 + (jj >> 3)) * 8 + row) * 8 + (jj & 7)] = f2bf(cn);
          if (s == 63) qf[row][jj] = hn;       // f32 h for final (qf done)
        }
      }
    }
    __syncthreads();

    if (s == 63) {    // ctx[b][e] = sum_t alpha_t * x[b,t,e]  (into P8 alias)
      float* __restrict__ ctxS = (float*)P8;
      #pragma unroll
      for (int p = 0; p < 4; ++p) {
        const int e = p * 64 + lane;
        float a = 0.f;
        const float* __restrict__ xr = x + (size_t)gb * 16384 + e;
        #pragma unroll 8
        for (int t = 0; t < 64; ++t) a = fmaf(scAl[b][t], xr[t * 256], a);
        ctxS[b * 256 + e] = a;
      }
      __syncthreads();
    }
  }

  // ---- final: out = [h, ctx] @ W_final.T + b_final ----
  {
    const float* __restrict__ ctxS = (const float*)P8;
    float o0 = 0.f, o1 = 0.f;
    #pragma unroll
    for (int kk = 0; kk < 8; ++kk) {
      const int k = kk * 64 + lane;
      const float v = (k < 256) ? qf[b][k] : ctxS[b * 256 + (k - 256)];
      o0 = fmaf(v, Wfin[k], o0);
      o1 = fmaf(v, Wfin[512 + k], o1);
    }
    o0 = wredsum(o0);
    o1 = wredsum(o1);
    if (lane == 0) {
      out[gb * 2 + 0] = o0 + bfin[0];
      out[gb * 2 + 1] = o1 + bfin[1];
    }
  }
}

// ---------------------------------------------------------------------------
extern "C" void kernel_launch(void* const* d_in, const int* in_sizes, int n_in,
                              void* d_out, int out_size, void* d_ws, size_t ws_size,
                              hipStream_t stream) {
  const float* x    = (const float*)d_in[0];
  const float* yh   = (const float*)d_in[1];
  const float* W1   = (const float*)d_in[2];
  const float* b1   = (const float*)d_in[3];
  const float* w2   = (const float*)d_in[4];
  // d_in[5] = b2: softmax-invariant -> unused
  const float* Wih  = (const float*)d_in[6];
  const float* bih  = (const float*)d_in[7];
  const float* Whh  = (const float*)d_in[8];
  const float* bhh  = (const float*)d_in[9];
  const float* Wfc  = (const float*)d_in[10];
  const float* bfc  = (const float*)d_in[11];
  const float* Wfin = (const float*)d_in[12];
  const float* bfin = (const float*)d_in[13];

  char* ws = (char*)d_ws;
  unsigned short* P    = (unsigned short*)(ws + 0);          // 67,108,864 B
  unsigned short* WB1  = (unsigned short*)(ws + 67108864);   //    262,144 B
  unsigned short* WBhh = (unsigned short*)(ws + 67371008);   //    524,288 B
  unsigned short* WB1e = (unsigned short*)(ws + 67895296);   //    131,072 B
  float* b1s   = (float*)(ws + 68026368);                    //      1,024 B
  float* Wihs  = (float*)(ws + 68027392);                    //      8,192 B
  float* gbias = (float*)(ws + 68035584);                    //      4,096 B
  float* yh2   = (float*)(ws + 68039680);                    //     16,384 B
  float* ey    = (float*)(ws + 68056064);                    //  1,048,576 B -> 69,104,640 total

  ktrans<<<1821, 256, 0, stream>>>(W1, b1, Wih, bih, Whh, bhh, Wfc, bfc, yh,
                                   WB1, WBhh, WB1e, b1s, Wihs, gbias, yh2);
  kpre<<<2048, 256, 0, stream>>>(x, WB1e, Wfc, P, ey);
  krecur<<<256, 512, 0, stream>>>(x, w2, WB1, WBhh, Wihs, gbias, b1s, yh2, ey, P,
                                  Wfin, bfin, (float*)d_out);
}

// Round 4
// 3879.832 us; speedup vs baseline: 2.6518x; 1.8218x over previous
//
#include <hip/hip_runtime.h>
#include <hip/hip_bf16.h>
#include <cstdint>
#include <cstddef>

#define LOG2E 1.44269504088896340736f

using f32x4 = __attribute__((ext_vector_type(4))) float;
using s16x8 = __attribute__((ext_vector_type(8))) short;

static __device__ __forceinline__ float bf2f(unsigned short u) {
  union { unsigned int i; float f; } v; v.i = ((unsigned int)u) << 16; return v.f;
}
static __device__ __forceinline__ unsigned short f2bf(float f) {
  union { float f; unsigned int i; } v; v.f = f;
  unsigned int r = v.i + 0x7fffu + ((v.i >> 16) & 1u);
  return (unsigned short)(r >> 16);
}
static __device__ __forceinline__ float wredmax(float v) {
  #pragma unroll
  for (int m = 32; m > 0; m >>= 1) v = fmaxf(v, __shfl_xor(v, m, 64));
  return v;
}
static __device__ __forceinline__ float wredsum(float v) {
  #pragma unroll
  for (int m = 32; m > 0; m >>= 1) v += __shfl_xor(v, m, 64);
  return v;
}

// ---------------------------------------------------------------------------
// Transform kernel (unchanged from R3).
// ---------------------------------------------------------------------------
__global__ void ktrans(const float* __restrict__ W1, const float* __restrict__ b1,
                       const float* __restrict__ Wih_in, const float* __restrict__ bih,
                       const float* __restrict__ Whh, const float* __restrict__ bhh,
                       const float* __restrict__ Wfc, const float* __restrict__ bfc,
                       const float* __restrict__ yhist,
                       unsigned short* __restrict__ WB1, unsigned short* __restrict__ WBhh,
                       unsigned short* __restrict__ WB1e, float* __restrict__ b1s,
                       float* __restrict__ Wihs, float* __restrict__ gbias,
                       float* __restrict__ yh2)
{
  int idx = blockIdx.x * 256 + threadIdx.x;
  const float TS = 2.f * LOG2E;
  if (idx < 131072) {                       // WB1: (k,e')
    int k = idx >> 8, e = idx & 255;
    WB1[((k >> 3) * 256 + e) * 8 + (k & 7)] = f2bf(TS * W1[e * 768 + k]);
    return;
  }
  idx -= 131072;
  if (idx < 262144) {                       // WBhh: (k,j)
    int k = idx >> 10, j = idx & 1023;
    float sc = ((j >> 8) == 2) ? TS : -LOG2E;
    WBhh[((k >> 3) * 1024 + j) * 8 + (k & 7)] = f2bf(sc * Whh[j * 256 + k]);
    return;
  }
  idx -= 262144;
  if (idx < 65536) {                        // WB1e: (k,e'), x part
    int k = idx >> 8, e = idx & 255;
    WB1e[((k >> 3) * 256 + e) * 8 + (k & 7)] = f2bf(TS * W1[e * 768 + 512 + k]);
    return;
  }
  idx -= 65536;
  if (idx < 256) { b1s[idx] = TS * b1[idx]; return; }
  idx -= 256;
  if (idx < 2048) {                         // Wihs (j,o)
    int j = idx >> 1;
    float sc = ((j >> 8) == 2) ? TS : -LOG2E;
    Wihs[idx] = sc * Wih_in[idx];
    return;
  }
  idx -= 2048;
  if (idx < 1024) {
    int j = idx;
    float sc = ((j >> 8) == 2) ? TS : -LOG2E;
    gbias[j] = sc * (bih[j] + bhh[j]);
    return;
  }
  idx -= 1024;
  if (idx < 4096) {                         // yh2 (b,o)
    int bq = idx >> 1, o = idx & 1;
    float a = bfc[o];
    for (int t = 0; t < 64; ++t) a = fmaf(yhist[bq * 64 + t], Wfc[o * 320 + 256 + t], a);
    yh2[idx] = a;
    return;
  }
}

// ---------------------------------------------------------------------------
// Precompute kernel (unchanged from R3, correctness-proven).
// ---------------------------------------------------------------------------
__global__ __launch_bounds__(256, 4) void kpre(
    const float* __restrict__ x, const unsigned short* __restrict__ WB1e,
    const float* __restrict__ Wfc,
    unsigned short* __restrict__ P, float* __restrict__ ey)
{
  __shared__ __align__(16) unsigned short xs[16384];
  const int bq = blockIdx.x;
  const int tid = threadIdx.x;
  const int w = tid >> 6, lane = tid & 63;
  const float* __restrict__ xb = x + (size_t)bq * 16384;

  #pragma unroll 4
  for (int it = 0; it < 16; ++it) {
    int idx = it * 256 + tid;
    float4 v = *(const float4*)(xb + (size_t)idx * 4);
    int t = idx >> 6, e0 = (idx & 63) * 4;
    unsigned long long pk = (unsigned long long)f2bf(v.x)
        | ((unsigned long long)f2bf(v.y) << 16)
        | ((unsigned long long)f2bf(v.z) << 32)
        | ((unsigned long long)f2bf(v.w) << 48);
    int ba = (t * 512 + e0 * 2) ^ ((t & 7) << 4);
    *(unsigned long long*)((char*)xs + ba) = pk;
  }
  __syncthreads();

  const int mt = w;
  const int fgrp = lane >> 4, fcol = lane & 15;
  const int trow = mt * 16 + fcol;
  s16x8 af[8];
  #pragma unroll
  for (int kb = 0; kb < 8; ++kb) {
    int e = kb * 32 + fgrp * 8;
    int ba = (trow * 512 + e * 2) ^ ((trow & 7) << 4);
    af[kb] = *(const s16x8*)((char*)xs + ba);
  }
  __syncthreads();

  unsigned short* __restrict__ Pst = xs;
  #pragma unroll
  for (int nt = 0; nt < 16; ++nt) {
    s16x8 bfr[8];
    #pragma unroll
    for (int kb = 0; kb < 8; ++kb)
      bfr[kb] = *(const s16x8*)&WB1e[(size_t)((kb * 4 + fgrp) * 256 + nt * 16 + fcol) * 8];
    f32x4 acc = {0.f, 0.f, 0.f, 0.f};
    #pragma unroll
    for (int kb = 0; kb < 8; ++kb)
      acc = __builtin_amdgcn_mfma_f32_16x16x32_bf16(af[kb], bfr[kb], acc, 0, 0, 0);
    const int ep = nt * 16 + fcol;
    #pragma unroll
    for (int r = 0; r < 4; ++r)
      Pst[(mt * 16 + fgrp * 4 + r) * 256 + ep] = f2bf(acc[r]);
  }
  __syncthreads();

  unsigned int* __restrict__ Pd = (unsigned int*)(P + (size_t)bq * 16384);
  #pragma unroll 4
  for (int d = tid; d < 8192; d += 256) {
    int f = d * 2;
    int ec = f >> 9, t = (f >> 3) & 63, i0 = f & 7;
    unsigned int lo = Pst[t * 256 + ec * 8 + i0];
    unsigned int hi = Pst[t * 256 + ec * 8 + i0 + 1];
    Pd[d] = lo | (hi << 16);
  }

  if (tid < 128) {
    int t = tid >> 1, o = tid & 1;
    float a = 0.f;
    const float* __restrict__ xr = xb + t * 256;
    const float* __restrict__ wr = Wfc + o * 320;
    #pragma unroll 4
    for (int e = 0; e < 256; ++e) a = fmaf(xr[e], wr[e], a);
    ey[((size_t)bq * 64 + t) * 2 + o] = a;
  }
}

// ---------------------------------------------------------------------------
// Recurrence v4: spill-proof. P = 16 NAMED s16x8 regs + 16 LDS chunks.
// All state in named scalars; A/B frags loaded inline. 3 barriers/step.
// ---------------------------------------------------------------------------
#define SIG(X) __builtin_amdgcn_rcpf(1.f + __builtin_amdgcn_exp2f(X))

#define SCCHUNK(PV, EC) do { \
  const float4 qa_ = *(const float4*)(qrow + (EC) * 8); \
  const float4 qc_ = *(const float4*)(qrow + (EC) * 8 + 4); \
  const float4 wa_ = *(const float4*)(w2f + (EC) * 8); \
  const float4 wc_ = *(const float4*)(w2f + (EC) * 8 + 4); \
  a0 = fmaf(wa_.x, SIG(bf2f((unsigned short)(PV)[0]) + qa_.x), a0); \
  a1 = fmaf(wa_.y, SIG(bf2f((unsigned short)(PV)[1]) + qa_.y), a1); \
  a2 = fmaf(wa_.z, SIG(bf2f((unsigned short)(PV)[2]) + qa_.z), a2); \
  a3 = fmaf(wa_.w, SIG(bf2f((unsigned short)(PV)[3]) + qa_.w), a3); \
  a0 = fmaf(wc_.x, SIG(bf2f((unsigned short)(PV)[4]) + qc_.x), a0); \
  a1 = fmaf(wc_.y, SIG(bf2f((unsigned short)(PV)[5]) + qc_.y), a1); \
  a2 = fmaf(wc_.z, SIG(bf2f((unsigned short)(PV)[6]) + qc_.z), a2); \
  a3 = fmaf(wc_.w, SIG(bf2f((unsigned short)(PV)[7]) + qc_.w), a3); \
} while (0)

#define SCL(EC) do { \
  const s16x8 pvL_ = *(const s16x8*)&Plds[b][(EC) - 16][lane][0]; \
  SCCHUNK(pvL_, EC); \
} while (0)

#define AH(KB) (*(const s16x8*)&hcA[(((KB) * 4 + fgrp) * 8 + frow) * 8])

#define GUNIT(U, S0, S1, S2, S3) do { \
  const size_t jb_ = (size_t)((((U) & 3) * 256 + ((U) >> 2) * 128 + w * 16 + fcol)) * 8; \
  const s16x8 wb0_ = *(const s16x8*)&WBhh[jb_ + (size_t)(0 * 4 + fgrp) * 8192]; \
  const s16x8 wb1_ = *(const s16x8*)&WBhh[jb_ + (size_t)(1 * 4 + fgrp) * 8192]; \
  const s16x8 wb2_ = *(const s16x8*)&WBhh[jb_ + (size_t)(2 * 4 + fgrp) * 8192]; \
  const s16x8 wb3_ = *(const s16x8*)&WBhh[jb_ + (size_t)(3 * 4 + fgrp) * 8192]; \
  const s16x8 wb4_ = *(const s16x8*)&WBhh[jb_ + (size_t)(4 * 4 + fgrp) * 8192]; \
  const s16x8 wb5_ = *(const s16x8*)&WBhh[jb_ + (size_t)(5 * 4 + fgrp) * 8192]; \
  const s16x8 wb6_ = *(const s16x8*)&WBhh[jb_ + (size_t)(6 * 4 + fgrp) * 8192]; \
  const s16x8 wb7_ = *(const s16x8*)&WBhh[jb_ + (size_t)(7 * 4 + fgrp) * 8192]; \
  G##U = (f32x4){gb_##U, gb_##U, gb_##U, gb_##U}; \
  S0; S1; S2; S3; \
  G##U = __builtin_amdgcn_mfma_f32_16x16x32_bf16(AH(0), wb0_, G##U, 0, 0, 0); \
  G##U = __builtin_amdgcn_mfma_f32_16x16x32_bf16(AH(1), wb1_, G##U, 0, 0, 0); \
  G##U = __builtin_amdgcn_mfma_f32_16x16x32_bf16(AH(2), wb2_, G##U, 0, 0, 0); \
  G##U = __builtin_amdgcn_mfma_f32_16x16x32_bf16(AH(3), wb3_, G##U, 0, 0, 0); \
  G##U = __builtin_amdgcn_mfma_f32_16x16x32_bf16(AH(4), wb4_, G##U, 0, 0, 0); \
  G##U = __builtin_amdgcn_mfma_f32_16x16x32_bf16(AH(5), wb5_, G##U, 0, 0, 0); \
  G##U = __builtin_amdgcn_mfma_f32_16x16x32_bf16(AH(6), wb6_, G##U, 0, 0, 0); \
  G##U = __builtin_amdgcn_mfma_f32_16x16x32_bf16(AH(7), wb7_, G##U, 0, 0, 0); \
} while (0)

#define PW(CG, R, CV, Gi, Gf, Gg, Go, w0i, w1i, w0f, w1f, w0g, w1g, w0o, w1o) do { \
  const int row_ = (drow0 + (R)) & 7; \
  const int jj_ = (CG) * 128 + w * 16 + fcol; \
  const float y0_ = yt[row_][0], y1_ = yt[row_][1]; \
  const float gi_ = (Gi)[R] + fmaf(w0i, y0_, (w1i) * y1_); \
  const float gf_ = (Gf)[R] + fmaf(w0f, y0_, (w1f) * y1_); \
  const float gg_ = (Gg)[R] + fmaf(w0g, y0_, (w1g) * y1_); \
  const float go_ = (Go)[R] + fmaf(w0o, y0_, (w1o) * y1_); \
  const float si_ = SIG(gi_); \
  const float sf_ = SIG(gf_); \
  const float tg_ = 1.f - 2.f * SIG(gg_); \
  const float so_ = SIG(go_); \
  const float cn_ = sf_ * (CV) + si_ * tg_; \
  (CV) = cn_; \
  const float th_ = 1.f - 2.f * SIG(2.f * LOG2E * cn_); \
  const float hn_ = so_ * th_; \
  if (lane < 32) { \
    hcA[((jj_ >> 3) * 8 + row_) * 8 + (jj_ & 7)] = f2bf(hn_); \
    hcA[((32 + (jj_ >> 3)) * 8 + row_) * 8 + (jj_ & 7)] = f2bf(cn_); \
    if (s == 63) qf[row_][jj_] = hn_; \
  } \
} while (0)

#define PLOADR(U) const s16x8 p##U = *(const s16x8*)(Pb + (size_t)((U) * 64 + lane) * 8);

#define WIGB(U) \
  const int j##U = (((U) & 3) * 256 + ((U) >> 2) * 128 + w * 16 + fcol); \
  const float wi0_##U = Wihs[2 * j##U]; \
  const float wi1_##U = Wihs[2 * j##U + 1]; \
  const float gb_##U = gbias[j##U];

__global__ __launch_bounds__(512, 1) void krecur(
    const float* __restrict__ x, const float* __restrict__ w2g,
    const unsigned short* __restrict__ WB1, const unsigned short* __restrict__ WBhh,
    const float* __restrict__ Wihs, const float* __restrict__ gbias,
    const float* __restrict__ b1s, const float* __restrict__ yh2,
    const float* __restrict__ ey, const unsigned short* __restrict__ P,
    const float* __restrict__ Wfin, const float* __restrict__ bfin,
    float* __restrict__ out)
{
  __shared__ __align__(16) unsigned short Plds[8][16][64][8]; // 128 KB (ec 16..31); ctx alias
  __shared__ __align__(16) unsigned short hcA[4096];          // 8 KB [k>>3][row][k&7]
  __shared__ __align__(16) float qf[8][256];                  // 8 KB; h(f32) stash at s=63
  __shared__ __align__(16) float w2f[256];                    // 1 KB
  __shared__ __align__(16) float scAl[8][64];                 // 2 KB
  __shared__ float yt[8][2];

  const int tid = threadIdx.x;
  const int w = tid >> 6, lane = tid & 63;
  const int b = w;                            // wave = batch row
  const int gbase = blockIdx.x * 8;
  const int gb = gbase + b;

  for (int i = tid; i < 4096; i += 512) hcA[i] = 0;
  if (tid < 256) w2f[tid] = w2g[tid];
  // P LDS chunks (ec 16..31) for all 8 rows; coalesced 16B loads
  for (int i = tid; i < 8192; i += 512) {
    int row = i >> 10, rem = i & 1023, ec = rem >> 6, t = rem & 63;
    *(s16x8*)&Plds[row][ec][t][0] =
        *(const s16x8*)(P + (size_t)(gbase + row) * 16384 + (size_t)((16 + ec) * 64 + t) * 8);
  }

  const int frow = lane & 7;
  const int fgrp = lane >> 4;
  const int fcol = lane & 15;
  const int drow0 = fgrp * 4;

  // P reg chunks ec 0..15 as 16 NAMED s16x8 (64 VGPR, cannot be demoted)
  const unsigned short* __restrict__ Pb = P + (size_t)gb * 16384;
  PLOADR(0)  PLOADR(1)  PLOADR(2)  PLOADR(3)
  PLOADR(4)  PLOADR(5)  PLOADR(6)  PLOADR(7)
  PLOADR(8)  PLOADR(9)  PLOADR(10) PLOADR(11)
  PLOADR(12) PLOADR(13) PLOADR(14) PLOADR(15)

  const float2 eyv = *(const float2*)(ey + ((size_t)gb * 64 + lane) * 2);
  const float yh0 = yh2[gb * 2], yh1 = yh2[gb * 2 + 1];
  const float b1r0 = b1s[(w * 2 + 0) * 16 + fcol];
  const float b1r1 = b1s[(w * 2 + 1) * 16 + fcol];

  WIGB(0) WIGB(1) WIGB(2) WIGB(3) WIGB(4) WIGB(5) WIGB(6) WIGB(7)

  float c0 = 0.f, c1 = 0.f, c2 = 0.f, c3 = 0.f;
  float c4 = 0.f, c5 = 0.f, c6 = 0.f, c7 = 0.f;

  __syncthreads();

  for (int s = 0; s < 64; ++s) {
    // ---- phase1: q = hc @ WB1^T + b1 (2 N-tiles/wave), A/B inline ----
    #pragma unroll
    for (int et2 = 0; et2 < 2; ++et2) {
      const int eb = (w * 2 + et2) * 16;
      f32x4 acc = {0.f, 0.f, 0.f, 0.f};
      #pragma unroll
      for (int kb = 0; kb < 16; ++kb) {
        const s16x8 bfr = *(const s16x8*)&WB1[(size_t)((kb * 4 + fgrp) * 256 + eb + fcol) * 8];
        acc = __builtin_amdgcn_mfma_f32_16x16x32_bf16(AH(kb), bfr, acc, 0, 0, 0);
      }
      if (lane < 32) {
        const float bb = et2 ? b1r1 : b1r0;
        #pragma unroll
        for (int r = 0; r < 4; ++r) qf[drow0 + r][eb + fcol] = acc[r] + bb;
      }
    }
    __syncthreads();

    // ---- phase2: 8 units = WBhh stream + 8 gate-MFMAs each, scores hidden ----
    float a0 = 0.f, a1 = 0.f, a2 = 0.f, a3 = 0.f;
    f32x4 G0, G1, G2, G3, G4, G5, G6, G7;
    const float* __restrict__ qrow = &qf[b][0];
    GUNIT(0, SCCHUNK(p0, 0),  SCCHUNK(p1, 1),  SCCHUNK(p2, 2),  SCCHUNK(p3, 3));
    GUNIT(1, SCCHUNK(p4, 4),  SCCHUNK(p5, 5),  SCCHUNK(p6, 6),  SCCHUNK(p7, 7));
    GUNIT(2, SCCHUNK(p8, 8),  SCCHUNK(p9, 9),  SCCHUNK(p10, 10), SCCHUNK(p11, 11));
    GUNIT(3, SCCHUNK(p12, 12), SCCHUNK(p13, 13), SCCHUNK(p14, 14), SCCHUNK(p15, 15));
    GUNIT(4, SCL(16), SCL(17), SCL(18), SCL(19));
    GUNIT(5, SCL(20), SCL(21), SCL(22), SCL(23));
    GUNIT(6, SCL(24), SCL(25), SCL(26), SCL(27));
    GUNIT(7, SCL(28), SCL(29), SCL(30), SCL(31));

    // softmax + ytilde
    {
      float sc = -2.f * ((a0 + a1) + (a2 + a3));
      float mx = wredmax(sc);
      float e_t = __builtin_amdgcn_exp2f((sc - mx) * LOG2E);
      float sm = wredsum(e_t);
      float alpha = e_t * __builtin_amdgcn_rcpf(sm);
      if (s == 63) scAl[b][lane] = alpha;
      float y0 = wredsum(alpha * eyv.x);
      float y1 = wredsum(alpha * eyv.y);
      if (lane == 0) { yt[b][0] = y0 + yh0; yt[b][1] = y1 + yh1; }
    }
    __syncthreads();

    // ---- phase3: + wi*yt, pointwise, state update (all named regs) ----
    PW(0, 0, c0, G0, G1, G2, G3, wi0_0, wi1_0, wi0_1, wi1_1, wi0_2, wi1_2, wi0_3, wi1_3);
    PW(0, 1, c1, G0, G1, G2, G3, wi0_0, wi1_0, wi0_1, wi1_1, wi0_2, wi1_2, wi0_3, wi1_3);
    PW(0, 2, c2, G0, G1, G2, G3, wi0_0, wi1_0, wi0_1, wi1_1, wi0_2, wi1_2, wi0_3, wi1_3);
    PW(0, 3, c3, G0, G1, G2, G3, wi0_0, wi1_0, wi0_1, wi1_1, wi0_2, wi1_2, wi0_3, wi1_3);
    PW(1, 0, c4, G4, G5, G6, G7, wi0_4, wi1_4, wi0_5, wi1_5, wi0_6, wi1_6, wi0_7, wi1_7);
    PW(1, 1, c5, G4, G5, G6, G7, wi0_4, wi1_4, wi0_5, wi1_5, wi0_6, wi1_6, wi0_7, wi1_7);
    PW(1, 2, c6, G4, G5, G6, G7, wi0_4, wi1_4, wi0_5, wi1_5, wi0_6, wi1_6, wi0_7, wi1_7);
    PW(1, 3, c7, G4, G5, G6, G7, wi0_4, wi1_4, wi0_5, wi1_5, wi0_6, wi1_6, wi0_7, wi1_7);
    __syncthreads();

    if (s == 63) {    // ctx into Plds alias (P is dead now)
      float* __restrict__ ctxS = (float*)Plds;
      #pragma unroll
      for (int p = 0; p < 4; ++p) {
        const int e = p * 64 + lane;
        float a = 0.f;
        const float* __restrict__ xr = x + (size_t)gb * 16384 + e;
        #pragma unroll 8
        for (int t = 0; t < 64; ++t) a = fmaf(scAl[b][t], xr[t * 256], a);
        ctxS[b * 256 + e] = a;
      }
      __syncthreads();
    }
  }

  // ---- final: out = [h, ctx] @ W_final.T + b_final ----
  {
    const float* __restrict__ ctxS = (const float*)Plds;
    float o0 = 0.f, o1 = 0.f;
    #pragma unroll
    for (int kk = 0; kk < 8; ++kk) {
      const int k = kk * 64 + lane;
      const float v = (k < 256) ? qf[b][k] : ctxS[b * 256 + (k - 256)];
      o0 = fmaf(v, Wfin[k], o0);
      o1 = fmaf(v, Wfin[512 + k], o1);
    }
    o0 = wredsum(o0);
    o1 = wredsum(o1);
    if (lane == 0) {
      out[gb * 2 + 0] = o0 + bfin[0];
      out[gb * 2 + 1] = o1 + bfin[1];
    }
  }
}

// ---------------------------------------------------------------------------
extern "C" void kernel_launch(void* const* d_in, const int* in_sizes, int n_in,
                              void* d_out, int out_size, void* d_ws, size_t ws_size,
                              hipStream_t stream) {
  const float* x    = (const float*)d_in[0];
  const float* yh   = (const float*)d_in[1];
  const float* W1   = (const float*)d_in[2];
  const float* b1   = (const float*)d_in[3];
  const float* w2   = (const float*)d_in[4];
  // d_in[5] = b2: softmax-invariant -> unused
  const float* Wih  = (const float*)d_in[6];
  const float* bih  = (const float*)d_in[7];
  const float* Whh  = (const float*)d_in[8];
  const float* bhh  = (const float*)d_in[9];
  const float* Wfc  = (const float*)d_in[10];
  const float* bfc  = (const float*)d_in[11];
  const float* Wfin = (const float*)d_in[12];
  const float* bfin = (const float*)d_in[13];

  char* ws = (char*)d_ws;
  unsigned short* P    = (unsigned short*)(ws + 0);          // 67,108,864 B
  unsigned short* WB1  = (unsigned short*)(ws + 67108864);   //    262,144 B
  unsigned short* WBhh = (unsigned short*)(ws + 67371008);   //    524,288 B
  unsigned short* WB1e = (unsigned short*)(ws + 67895296);   //    131,072 B
  float* b1s   = (float*)(ws + 68026368);                    //      1,024 B
  float* Wihs  = (float*)(ws + 68027392);                    //      8,192 B
  float* gbias = (float*)(ws + 68035584);                    //      4,096 B
  float* yh2   = (float*)(ws + 68039680);                    //     16,384 B
  float* ey    = (float*)(ws + 68056064);                    //  1,048,576 B -> 69,104,640 total

  ktrans<<<1821, 256, 0, stream>>>(W1, b1, Wih, bih, Whh, bhh, Wfc, bfc, yh,
                                   WB1, WBhh, WB1e, b1s, Wihs, gbias, yh2);
  kpre<<<2048, 256, 0, stream>>>(x, WB1e, Wfc, P, ey);
  krecur<<<256, 512, 0, stream>>>(x, w2, WB1, WBhh, Wihs, gbias, b1s, yh2, ey, P,
                                  Wfin, bfin, (float*)d_out);
}